// Round 3
// baseline (4458.146 us; speedup 1.0000x reference)
//
#include <hip/hip_runtime.h>
#include <math.h>

// ---------------------------------------------------------------------------
// VQ-VAE forward, fp32.
// Shapes: x[256,3,64,64] -> h1[256,64,32,32] -> h2[256,128,16,16]
//         -> encoded[256,256,16,16] -> VQ (rows = (n,c), D=256 spatial)
//         -> dec1[256,128,32,32] -> dec2 (fused with 1x1+sigmoid) -> decoded[256,3,64,64]
// d_out: decoded | encoded | quantized | vq_loss | perplexity  (float32)
// R3: dec2 restructured — 4 positions/thread x 32 couts, weight LDS layout
//     [c][co][cl^swz][tap] (conflict-free), 16 FMA per ds_read_b128.
// ---------------------------------------------------------------------------

__global__ __launch_bounds__(256) void zero_k(int* hist, double* lacc){
  int t = threadIdx.x;
  hist[t] = 0;
  if(t==0) *lacc = 0.0;
}

// codebook [256k][256d] -> cT[d][k], cn[k] = sum_d cb[k][d]^2
__global__ __launch_bounds__(256) void prep_codebook_k(const float* __restrict__ cb,
                                                       float* __restrict__ cT,
                                                       float* __restrict__ cn){
  int k = blockIdx.x, d = threadIdx.x;
  float v = cb[k*256 + d];
  cT[d*256 + k] = v;
  __shared__ float red[256];
  red[d] = v*v;
  __syncthreads();
  for(int s=128; s>0; s>>=1){ if(d<s) red[d] += red[d+s]; __syncthreads(); }
  if(d==0) cn[k] = red[0];
}

// w3 [256co][128ci] -> wT3[ci][co]
__global__ __launch_bounds__(256) void prep_wT3_k(const float* __restrict__ w3,
                                                  float* __restrict__ wT3){
  int ci = blockIdx.x, co = threadIdx.x;
  wT3[ci*256 + co] = w3[co*128 + ci];
}

// Weight re-layouts:
//  conv2:  wc2[ci64][co128][k16]            = w2[co][ci][k]
//  dec1:   wd1[cl4][ci256][co128][tap4]     = dw1[ci][co][kh(a,i)][kw(b,j)]
//  dec2:   wd2[cl4][ci128][co64][tap4]      = dw2[ci][co][kh(a,i)][kw(b,j)]
//  class cl = a*2+b with a = oh&1, b = ow&1; tap = i*2+j reads input (ihb-i, iwb-j).
//  a==0 -> kh = 1+2i ; a==1 -> kh = 2i  (same for kw/b).
__global__ __launch_bounds__(256) void prep_weights_k(const float* __restrict__ w2,
                                                      const float* __restrict__ dw1,
                                                      const float* __restrict__ dw2,
                                                      float* __restrict__ wc2,
                                                      float* __restrict__ wd1,
                                                      float* __restrict__ wd2){
  int gid = blockIdx.x*256 + threadIdx.x;
  if(gid < 131072){
    int id = gid; int ci = id>>11, co = (id>>4)&127, k = id&15;
    wc2[id] = w2[((co<<6) + ci)*16 + k];
  } else if(gid < 655360){
    int id = gid - 131072;
    int cl = id>>17, ci = (id>>9)&255, co = (id>>2)&127, tap = id&3;
    int a = cl>>1, b = cl&1, i = tap>>1, j = tap&1;
    int kh = a ? 2*i : 1+2*i;
    int kw = b ? 2*j : 1+2*j;
    wd1[id] = dw1[((ci<<7) + co)*16 + kh*4 + kw];
  } else {
    int id = gid - 655360;
    int cl = id>>15, ci = (id>>8)&127, co = (id>>2)&63, tap = id&3;
    int a = cl>>1, b = cl&1, i = tap>>1, j = tap&1;
    int kh = a ? 2*i : 1+2*i;
    int kw = b ? 2*j : 1+2*j;
    wd2[id] = dw2[((ci<<6) + co)*16 + kh*4 + kw];
  }
}

// conv1: 3->64, k4 s2 p1, ReLU.  grid (4, 256n), block 256.
__global__ __launch_bounds__(256) void conv1_k(const float* __restrict__ x,
                                               const float* __restrict__ w1,
                                               const float* __restrict__ b1,
                                               float* __restrict__ h1){
  __shared__ __align__(16) float wl[64*48];
  __shared__ float bl[64];
  int n = blockIdx.y, qd = blockIdx.x, t = threadIdx.x;
  for(int j=t; j<3072; j+=256) wl[j] = w1[j];
  if(t < 64) bl[t] = b1[t];
  __syncthreads();
  int oh = qd*8 + (t>>5), ow = t&31;
  const float* xb = x + n*3*4096;
  float patch[48];
  #pragma unroll
  for(int c=0;c<3;c++)
    #pragma unroll
    for(int kh=0;kh<4;kh++){
      int ih = 2*oh - 1 + kh;
      bool vr = (unsigned)ih < 64u;
      #pragma unroll
      for(int kw=0;kw<4;kw++){
        int iw = 2*ow - 1 + kw;
        patch[c*16 + kh*4 + kw] = (vr && (unsigned)iw<64u) ? xb[c*4096 + ih*64 + iw] : 0.f;
      }
    }
  float* hb = h1 + (size_t)n*64*1024 + oh*32 + ow;
  for(int co=0; co<64; co++){
    float acc = bl[co];
    #pragma unroll
    for(int k2=0;k2<48;k2++) acc += patch[k2]*wl[co*48 + k2];
    hb[co*1024] = fmaxf(acc, 0.f);
  }
}

// conv2: 64->128, k4 s2 p1, ReLU.  grid (2 halves, 256n), block 256.
// thread: 4 spatial positions x 16 couts.
__global__ __launch_bounds__(256) void conv2_k(const float* __restrict__ h1,
                                               const float* __restrict__ wp,
                                               const float* __restrict__ b2,
                                               float* __restrict__ h2){
  __shared__ __align__(16) float hc[8*1024];
  __shared__ __align__(16) float wc[8*64*16];
  int n = blockIdx.y, half = blockIdx.x, t = threadIdx.x;
  int co0 = half*64;
  int pg = t&63, cg = t>>6;
  int ow = pg&15;
  float acc[4][16] = {};
  const float* h1b = h1 + (size_t)n*65536;
  for(int ci0=0; ci0<64; ci0+=8){
    __syncthreads();
    #pragma unroll
    for(int j=0;j<32;j++){ int f = j*256+t; hc[f] = h1b[((ci0 + (f>>10))<<10) + (f&1023)]; }
    #pragma unroll
    for(int j=0;j<32;j++){ int f = j*256+t; int c = f>>10, r = f&1023;
      wc[f] = wp[(((ci0+c)<<7) + co0)*16 + r]; }
    __syncthreads();
    for(int c=0;c<8;c++){
      float patch[4][16];
      #pragma unroll
      for(int j=0;j<4;j++){
        int oh = (pg>>4) + 4*j;
        #pragma unroll
        for(int kh=0;kh<4;kh++){
          int ih = 2*oh - 1 + kh;
          bool vr = (unsigned)ih < 32u;
          #pragma unroll
          for(int kw=0;kw<4;kw++){
            int iw = 2*ow - 1 + kw;
            patch[j][kh*4+kw] = (vr && (unsigned)iw<32u) ? hc[(c<<10) + (ih<<5) + iw] : 0.f;
          }
        }
      }
      #pragma unroll
      for(int co=0;co<16;co++){
        const float4* w4 = (const float4*)&wc[(c<<10) + ((cg*16+co)<<4)];
        float4 wa = w4[0], wb = w4[1], wcv = w4[2], wd = w4[3];
        #pragma unroll
        for(int j=0;j<4;j++){
          float s = patch[j][0]*wa.x + patch[j][1]*wa.y + patch[j][2]*wa.z + patch[j][3]*wa.w;
          s += patch[j][4]*wb.x + patch[j][5]*wb.y + patch[j][6]*wb.z + patch[j][7]*wb.w;
          s += patch[j][8]*wcv.x + patch[j][9]*wcv.y + patch[j][10]*wcv.z + patch[j][11]*wcv.w;
          s += patch[j][12]*wd.x + patch[j][13]*wd.y + patch[j][14]*wd.z + patch[j][15]*wd.w;
          acc[j][co] += s;
        }
      }
    }
  }
  #pragma unroll
  for(int co=0;co<16;co++){
    int coa = co0 + cg*16 + co;
    float bb = b2[coa];
    #pragma unroll
    for(int j=0;j<4;j++){
      h2[(size_t)(n*128 + coa)*256 + pg + 64*j] = fmaxf(acc[j][co] + bb, 0.f);
    }
  }
}

// conv3 (1x1): 128->256, no relu.  grid (4 co-blocks, 256n), block 256 = spatial.
__global__ __launch_bounds__(256) void conv3_k(const float* __restrict__ h2,
                                               const float* __restrict__ wT3,
                                               const float* __restrict__ b3,
                                               float* __restrict__ enc){
  __shared__ __align__(16) float hcs[32*256];
  __shared__ __align__(16) float wcs[32*64];
  int n = blockIdx.y, cb4 = blockIdx.x, t = threadIdx.x;
  int co0 = cb4*64;
  float acc[64] = {};
  for(int ci0=0; ci0<128; ci0+=32){
    __syncthreads();
    #pragma unroll
    for(int j=0;j<32;j++){ int f=j*256+t; hcs[f] = h2[(size_t)(n*128 + ci0 + (f>>8))*256 + (f&255)]; }
    #pragma unroll
    for(int j=0;j<8;j++){ int f=j*256+t; wcs[f] = wT3[(ci0 + (f>>6))*256 + co0 + (f&63)]; }
    __syncthreads();
    for(int c=0;c<32;c++){
      float e = hcs[(c<<8) + t];
      const float4* w4 = (const float4*)&wcs[c<<6];
      #pragma unroll
      for(int q=0;q<16;q++){
        float4 w = w4[q];
        acc[4*q+0] += e*w.x; acc[4*q+1] += e*w.y; acc[4*q+2] += e*w.z; acc[4*q+3] += e*w.w;
      }
    }
  }
  for(int co=0;co<64;co++)
    enc[(size_t)(n*256 + co0 + co)*256 + t] = acc[co] + b3[co0+co];
}

// VQ argmin over 256 codes; 16 rows per block; thread = code.
__global__ __launch_bounds__(256) void vq_argmin_k(const float* __restrict__ enc,
                                                   const float* __restrict__ cT,
                                                   const float* __restrict__ cn,
                                                   int* __restrict__ idx){
  __shared__ __align__(16) float el[16*32];
  __shared__ float dl[16*256];
  int r0 = blockIdx.x*16, t = threadIdx.x;
  float acc[16] = {};
  for(int d0=0; d0<256; d0+=32){
    __syncthreads();
    #pragma unroll
    for(int j=0;j<2;j++){ int f=j*256+t; el[f] = enc[(size_t)(r0 + (f>>5))*256 + d0 + (f&31)]; }
    __syncthreads();
    float ck[32];
    #pragma unroll
    for(int d=0; d<32; d++) ck[d] = cT[(d0+d)*256 + t];
    #pragma unroll
    for(int r=0;r<16;r++){
      const float4* e4 = (const float4*)&el[r*32];
      float s = 0.f;
      #pragma unroll
      for(int q=0;q<8;q++){
        float4 e = e4[q];
        s += e.x*ck[4*q] + e.y*ck[4*q+1] + e.z*ck[4*q+2] + e.w*ck[4*q+3];
      }
      acc[r] += s;
    }
  }
  float cnk = cn[t];
  __syncthreads();
  #pragma unroll
  for(int r=0;r<16;r++) dl[r*256 + t] = cnk - 2.f*acc[r];
  __syncthreads();
  int w = t>>6, l = t&63;
  for(int rr=0; rr<4; rr++){
    int r = w*4 + rr;
    float bv = dl[r*256 + l]; int bk = l;
    for(int q=1;q<4;q++){
      float v = dl[r*256 + q*64 + l]; int k = q*64 + l;
      if(v < bv || (v == bv && k < bk)){ bv = v; bk = k; }
    }
    for(int s=1;s<64;s<<=1){
      float ov = __shfl_xor(bv, s);
      int   ok = __shfl_xor(bk, s);
      if(ov < bv || (ov == bv && ok < bk)){ bv = ov; bk = ok; }
    }
    if(l==0) idx[r0 + r] = bk;
  }
}

// quantized = codebook[idx], and sum of (q-e)^2 for the loss.
__global__ __launch_bounds__(256) void quant_k(const float* __restrict__ enc,
                                               const float* __restrict__ cb,
                                               const int* __restrict__ idx,
                                               float* __restrict__ qnt,
                                               double* __restrict__ lacc){
  int g = blockIdx.x*256 + threadIdx.x;
  size_t base = (size_t)g*4;
  int r = (int)(base >> 8), d = (int)(base & 255);
  int k = idx[r];
  float4 e = *(const float4*)(enc + base);
  float4 q = *(const float4*)(cb + k*256 + d);
  *(float4*)(qnt + base) = q;
  float dx = q.x-e.x, dy = q.y-e.y, dz = q.z-e.z, dw = q.w-e.w;
  float s = dx*dx + dy*dy + dz*dz + dw*dw;
  for(int o=1;o<64;o<<=1) s += __shfl_xor(s, o);
  if((threadIdx.x & 63) == 0) atomicAdd(lacc, (double)s);
}

__global__ __launch_bounds__(256) void hist_k(const int* __restrict__ idx, int* __restrict__ hist){
  __shared__ int hl[256];
  int t = threadIdx.x;
  hl[t] = 0; __syncthreads();
  for(int j=0;j<8;j++) atomicAdd(&hl[idx[blockIdx.x*2048 + j*256 + t]], 1);
  __syncthreads();
  if(hl[t]) atomicAdd(&hist[t], hl[t]);
}

__global__ __launch_bounds__(256) void final_k(const int* __restrict__ hist,
                                               const double* __restrict__ lacc,
                                               float* __restrict__ out_lp){
  __shared__ float red[256];
  int t = threadIdx.x;
  float p = hist[t] * (1.f/65536.f);
  red[t] = p * logf(p + 1e-10f);
  __syncthreads();
  for(int s=128; s>0; s>>=1){ if(t<s) red[t] += red[t+s]; __syncthreads(); }
  if(t==0){
    out_lp[0] = 1.25f * (float)(*lacc / 16777216.0);
    out_lp[1] = expf(-red[0]);
  }
}

// dec1: convT 256->128 k4 s2 p1, ReLU. grid (8 co-blocks, 256n), block 256.
// thread: ow = t&31, ohb = t>>5; positions oh = ohb + 8j (j<4); 16 couts.
__global__ __launch_bounds__(256) void dec1_k(const float* __restrict__ qnt,
                                              const float* __restrict__ wp,
                                              const float* __restrict__ db1,
                                              float* __restrict__ d1){
  __shared__ __align__(16) float qc[8*256];
  __shared__ __align__(16) float wl[4*8*16*4];
  int n = blockIdx.y, cblk = blockIdx.x, t = threadIdx.x;
  int co0 = cblk*16;
  int ow = t&31, ohb = t>>5;
  int b = ow&1;
  int iwb = (ow + b) >> 1;
  bool mw0 = iwb < 16, mw1 = iwb >= 1;
  int iw0 = mw0 ? iwb : 0, iw1 = mw1 ? iwb-1 : 0;
  int a = ohb & 1;
  int cl = (a<<1) | b;
  int ihb0 = (ohb + a) >> 1;
  float acc[4][16] = {};
  for(int ci0=0; ci0<256; ci0+=8){
    __syncthreads();
    #pragma unroll
    for(int j=0;j<8;j++){ int f=j*256+t; qc[f] = qnt[(size_t)(n*256 + ci0 + (f>>8))*256 + (f&255)]; }
    #pragma unroll
    for(int j=0;j<8;j++){ int f=j*256+t; int c2 = f>>9, rest = f&511; int c = rest>>6, rc = rest&63;
      wl[f] = wp[(size_t)(c2*256 + ci0 + c)*512 + co0*4 + rc]; }
    __syncthreads();
    for(int c=0;c<8;c++){
      float patch[4][4];
      #pragma unroll
      for(int j=0;j<4;j++){
        int ihb = ihb0 + 4*j;
        bool mh0 = ihb < 16, mh1 = ihb >= 1;
        int r0i = mh0 ? ihb : 0, r1i = mh1 ? ihb-1 : 0;
        patch[j][0] = (mh0 && mw0) ? qc[(c<<8) + (r0i<<4) + iw0] : 0.f;
        patch[j][1] = (mh0 && mw1) ? qc[(c<<8) + (r0i<<4) + iw1] : 0.f;
        patch[j][2] = (mh1 && mw0) ? qc[(c<<8) + (r1i<<4) + iw0] : 0.f;
        patch[j][3] = (mh1 && mw1) ? qc[(c<<8) + (r1i<<4) + iw1] : 0.f;
      }
      #pragma unroll
      for(int co=0;co<16;co++){
        const float4 w = *(const float4*)&wl[(cl<<9) + (c<<6) + (co<<2)];
        #pragma unroll
        for(int j=0;j<4;j++)
          acc[j][co] += patch[j][0]*w.x + patch[j][1]*w.y + patch[j][2]*w.z + patch[j][3]*w.w;
      }
    }
  }
  #pragma unroll
  for(int co=0;co<16;co++){
    float bb = db1[co0+co];
    #pragma unroll
    for(int j=0;j<4;j++){
      int oh = ohb + 8*j;
      d1[(size_t)(n*128 + co0 + co)*1024 + oh*32 + ow] = fmaxf(acc[j][co] + bb, 0.f);
    }
  }
}

// dec2: convT 128->64 k4 s2 p1 + ReLU, fused with dec3 (1x1 64->3) + sigmoid.
// grid (8 oh-tiles, 256n), block 256.
// thread: ow=t&63, s=t>>6: ch=s&1 (co half: 32 couts), pg=s>>1 (oh parity);
// 4 positions oh = oh0 + pg + 2q (q<4). Weight LDS [c][co][cl^(co&3)][tap],
// conflict-free; one float4 weight read feeds 16 FMAs.
__global__ __launch_bounds__(256) void dec2_k(const float* __restrict__ d1,
                                              const float* __restrict__ wp,
                                              const float* __restrict__ db2,
                                              const float* __restrict__ dw3,
                                              const float* __restrict__ db3,
                                              float* __restrict__ dec){
  __shared__ __align__(16) float dc[8*192];     // [c][6 rows][32]; reused as psum buffer in epilogue
  __shared__ __align__(16) float wl[8*64*16];   // [c][co][cl'][tap], 32 KB
  __shared__ float w3l[195];
  int n = blockIdx.y, tile = blockIdx.x, t = threadIdx.x;
  int oh0 = tile*8;
  if(t < 192) w3l[t] = dw3[t];
  if(t < 3)   w3l[192+t] = db3[t];
  int ow = t&63, s = t>>6;
  int ch = s&1, pg = s>>1;
  int b = ow&1;
  int iwb = (ow + b) >> 1;
  bool mw0 = iwb < 32, mw1 = iwb >= 1;
  int iw0 = mw0 ? iwb : 0, iw1 = mw1 ? iwb-1 : 0;
  int cl = (pg<<1) | b;
  // per-(co&3) pre-swizzled word offsets for the cl position
  int cx0 = ((cl^0)<<2), cx1 = ((cl^1)<<2), cx2 = ((cl^2)<<2), cx3 = ((cl^3)<<2);
  int ihr0 = oh0/2 - 1;
  float acc[4][32] = {};
  for(int ci0=0; ci0<128; ci0+=8){
    __syncthreads();
    #pragma unroll
    for(int j=0;j<6;j++){
      int f = j*256+t;
      int c = f/192, rest = f%192;
      int rr = rest>>5, iw = rest&31;
      int ih = ihr0 + rr;
      dc[c*192 + rest] = ((unsigned)ih < 32u) ? d1[(size_t)(n*128 + ci0 + c)*1024 + ih*32 + iw] : 0.f;
    }
    // stage weights: [cl][ci][co][tap] global -> [c][co][cl^(co&3)][tap] LDS
    #pragma unroll
    for(int j=0;j<8;j++){
      int f = j*256+t;
      int cls = f>>9, cs = (f>>6)&7, cos = f&63;
      float4 w = *(const float4*)&wp[(size_t)((cls*128 + ci0 + cs)<<8) + (cos<<2)];
      *(float4*)&wl[(cs<<10) + (cos<<4) + (((cls^(cos&3)))<<2)] = w;
    }
    __syncthreads();
    for(int c=0;c<8;c++){
      // rows pg..pg+4 at cols iw0/iw1 (positions q share rows)
      float pr[5][2];
      #pragma unroll
      for(int r=0;r<5;r++){
        pr[r][0] = mw0 ? dc[c*192 + (pg+r)*32 + iw0] : 0.f;
        pr[r][1] = mw1 ? dc[c*192 + (pg+r)*32 + iw1] : 0.f;
      }
      #pragma unroll
      for(int co=0;co<32;co++){
        int coa = (ch<<5) + co;
        int cx = ((coa&3)==0) ? cx0 : ((coa&3)==1) ? cx1 : ((coa&3)==2) ? cx2 : cx3;
        const float4 w = *(const float4*)&wl[(c<<10) + (coa<<4) + cx];
        #pragma unroll
        for(int q=0;q<4;q++)
          acc[q][co] += pr[q+1][0]*w.x + pr[q+1][1]*w.y + pr[q][0]*w.z + pr[q][1]*w.w;
      }
    }
  }
  // bias + ReLU
  #pragma unroll
  for(int co=0;co<32;co++){
    float bb = db2[(ch<<5)+co];
    #pragma unroll
    for(int q=0;q<4;q++) acc[q][co] = fmaxf(acc[q][co] + bb, 0.f);
  }
  // partial 1x1 (dec3) over this thread's 32 couts
  float z[4][3];
  #pragma unroll
  for(int q=0;q<4;q++)
    #pragma unroll
    for(int cp=0;cp<3;cp++){
      float sv = 0.f;
      #pragma unroll
      for(int co=0;co<32;co++) sv += acc[q][co]*w3l[((ch<<5)+co)*3+cp];
      z[q][cp] = sv;
    }
  __syncthreads();            // dc reads in main loop fully done
  int slot = ((pg<<6)+ow)*12;
  if(ch==1){
    #pragma unroll
    for(int q=0;q<4;q++)
      #pragma unroll
      for(int cp=0;cp<3;cp++) dc[slot + q*3 + cp] = z[q][cp];
  }
  __syncthreads();
  if(ch==0){
    #pragma unroll
    for(int q=0;q<4;q++){
      int oh = oh0 + pg + 2*q;
      #pragma unroll
      for(int cp=0;cp<3;cp++){
        float zz = z[q][cp] + dc[slot + q*3 + cp] + w3l[192+cp];
        dec[(size_t)(n*3 + cp)*4096 + oh*64 + ow] = 1.f/(1.f + expf(-zz));
      }
    }
  }
}

extern "C" void kernel_launch(void* const* d_in, const int* in_sizes, int n_in,
                              void* d_out, int out_size, void* d_ws, size_t ws_size,
                              hipStream_t stream) {
  const float* x   = (const float*)d_in[0];
  const float* ew1 = (const float*)d_in[1];
  const float* eb1 = (const float*)d_in[2];
  const float* ew2 = (const float*)d_in[3];
  const float* eb2 = (const float*)d_in[4];
  const float* ew3 = (const float*)d_in[5];
  const float* eb3 = (const float*)d_in[6];
  const float* cb  = (const float*)d_in[7];
  const float* dw1 = (const float*)d_in[8];
  const float* db1 = (const float*)d_in[9];
  const float* dw2 = (const float*)d_in[10];
  const float* db2 = (const float*)d_in[11];
  const float* dw3 = (const float*)d_in[12];
  const float* db3 = (const float*)d_in[13];

  float* out = (float*)d_out;
  float* dec = out;                           // 3,145,728
  float* enc = out + 3145728;                 // 16,777,216
  float* qnt = out + 19922944;                // 16,777,216
  float* lp  = out + 36700160;                // loss, perplexity

  float* ws = (float*)d_ws;
  float* d1buf = ws;                          // 33,554,432 floats (h1 aliases front)
  float* h1    = ws;                          // 16,777,216 (dead before dec1 writes)
  float* h2    = qnt;                         // reuse quantized slot (dead before quant_k)
  size_t o = 33554432;
  float* wc2p = ws + o; o += 131072;
  float* wd1p = ws + o; o += 524288;
  float* wd2p = ws + o; o += 131072;
  float* cT   = ws + o; o += 65536;
  float* cn   = ws + o; o += 256;
  float* wT3  = ws + o; o += 32768;
  int*   idx  = (int*)(ws + o); o += 65536;
  int*   hist = (int*)(ws + o); o += 256;
  double* lacc = (double*)(ws + o);

  zero_k<<<1, 256, 0, stream>>>(hist, lacc);
  prep_codebook_k<<<256, 256, 0, stream>>>(cb, cT, cn);
  prep_wT3_k<<<128, 256, 0, stream>>>(ew3, wT3);
  prep_weights_k<<<3072, 256, 0, stream>>>(ew2, dw1, dw2, wc2p, wd1p, wd2p);

  conv1_k<<<dim3(4,256), 256, 0, stream>>>(x, ew1, eb1, h1);
  conv2_k<<<dim3(2,256), 256, 0, stream>>>(h1, wc2p, eb2, h2);
  conv3_k<<<dim3(4,256), 256, 0, stream>>>(h2, wT3, eb3, enc);
  vq_argmin_k<<<4096, 256, 0, stream>>>(enc, cT, cn, idx);
  quant_k<<<16384, 256, 0, stream>>>(enc, cb, idx, qnt, lacc);
  hist_k<<<32, 256, 0, stream>>>(idx, hist);
  dec1_k<<<dim3(8,256), 256, 0, stream>>>(qnt, wd1p, db1, d1buf);
  dec2_k<<<dim3(8,256), 256, 0, stream>>>(d1buf, wd2p, db2, dw3, db3, dec);
  final_k<<<1, 256, 0, stream>>>(hist, lacc, lp);
}

// Round 5
// 3994.793 us; speedup vs baseline: 1.1160x; 1.1160x over previous
//
#include <hip/hip_runtime.h>
#include <math.h>

// ---------------------------------------------------------------------------
// VQ-VAE forward, fp32.
// Shapes: x[256,3,64,64] -> h1[256,64,32,32] -> h2[256,128,16,16]
//         -> encoded[256,256,16,16] -> VQ (rows = (n,c), D=256 spatial)
//         -> dec1[256,128,32,32] -> dec2 (fused with 1x1+sigmoid) -> decoded[256,3,64,64]
// d_out: decoded | encoded | quantized | vq_loss | perplexity  (float32)
// R4: dec2 = 4 pos x 16 co/thread (acc 64 VGPR, 4 waves/SIMD), swizzled
//     conflict-free weight LDS, halo-staged input (no masks in inner loop).
//     dec1 gets the same cl^(co&3) weight swizzle.
// ---------------------------------------------------------------------------

__global__ __launch_bounds__(256) void zero_k(int* hist, double* lacc){
  int t = threadIdx.x;
  hist[t] = 0;
  if(t==0) *lacc = 0.0;
}

// codebook [256k][256d] -> cT[d][k], cn[k] = sum_d cb[k][d]^2
__global__ __launch_bounds__(256) void prep_codebook_k(const float* __restrict__ cb,
                                                       float* __restrict__ cT,
                                                       float* __restrict__ cn){
  int k = blockIdx.x, d = threadIdx.x;
  float v = cb[k*256 + d];
  cT[d*256 + k] = v;
  __shared__ float red[256];
  red[d] = v*v;
  __syncthreads();
  for(int s=128; s>0; s>>=1){ if(d<s) red[d] += red[d+s]; __syncthreads(); }
  if(d==0) cn[k] = red[0];
}

// w3 [256co][128ci] -> wT3[ci][co]
__global__ __launch_bounds__(256) void prep_wT3_k(const float* __restrict__ w3,
                                                  float* __restrict__ wT3){
  int ci = blockIdx.x, co = threadIdx.x;
  wT3[ci*256 + co] = w3[co*128 + ci];
}

// Weight re-layouts:
//  conv2:  wc2[ci64][co128][k16]            = w2[co][ci][k]
//  dec1:   wd1[cl4][ci256][co128][tap4]     = dw1[ci][co][kh(a,i)][kw(b,j)]
//  dec2:   wd2[cl4][ci128][co64][tap4]      = dw2[ci][co][kh(a,i)][kw(b,j)]
//  class cl = a*2+b with a = oh&1, b = ow&1; tap = i*2+j reads input (ihb-i, iwb-j).
//  a==0 -> kh = 1+2i ; a==1 -> kh = 2i  (same for kw/b).
__global__ __launch_bounds__(256) void prep_weights_k(const float* __restrict__ w2,
                                                      const float* __restrict__ dw1,
                                                      const float* __restrict__ dw2,
                                                      float* __restrict__ wc2,
                                                      float* __restrict__ wd1,
                                                      float* __restrict__ wd2){
  int gid = blockIdx.x*256 + threadIdx.x;
  if(gid < 131072){
    int id = gid; int ci = id>>11, co = (id>>4)&127, k = id&15;
    wc2[id] = w2[((co<<6) + ci)*16 + k];
  } else if(gid < 655360){
    int id = gid - 131072;
    int cl = id>>17, ci = (id>>9)&255, co = (id>>2)&127, tap = id&3;
    int a = cl>>1, b = cl&1, i = tap>>1, j = tap&1;
    int kh = a ? 2*i : 1+2*i;
    int kw = b ? 2*j : 1+2*j;
    wd1[id] = dw1[((ci<<7) + co)*16 + kh*4 + kw];
  } else {
    int id = gid - 655360;
    int cl = id>>15, ci = (id>>8)&127, co = (id>>2)&63, tap = id&3;
    int a = cl>>1, b = cl&1, i = tap>>1, j = tap&1;
    int kh = a ? 2*i : 1+2*i;
    int kw = b ? 2*j : 1+2*j;
    wd2[id] = dw2[((ci<<6) + co)*16 + kh*4 + kw];
  }
}

// conv1: 3->64, k4 s2 p1, ReLU.  grid (4, 256n), block 256.
__global__ __launch_bounds__(256) void conv1_k(const float* __restrict__ x,
                                               const float* __restrict__ w1,
                                               const float* __restrict__ b1,
                                               float* __restrict__ h1){
  __shared__ __align__(16) float wl[64*48];
  __shared__ float bl[64];
  int n = blockIdx.y, qd = blockIdx.x, t = threadIdx.x;
  for(int j=t; j<3072; j+=256) wl[j] = w1[j];
  if(t < 64) bl[t] = b1[t];
  __syncthreads();
  int oh = qd*8 + (t>>5), ow = t&31;
  const float* xb = x + n*3*4096;
  float patch[48];
  #pragma unroll
  for(int c=0;c<3;c++)
    #pragma unroll
    for(int kh=0;kh<4;kh++){
      int ih = 2*oh - 1 + kh;
      bool vr = (unsigned)ih < 64u;
      #pragma unroll
      for(int kw=0;kw<4;kw++){
        int iw = 2*ow - 1 + kw;
        patch[c*16 + kh*4 + kw] = (vr && (unsigned)iw<64u) ? xb[c*4096 + ih*64 + iw] : 0.f;
      }
    }
  float* hb = h1 + (size_t)n*64*1024 + oh*32 + ow;
  for(int co=0; co<64; co++){
    float acc = bl[co];
    #pragma unroll
    for(int k2=0;k2<48;k2++) acc += patch[k2]*wl[co*48 + k2];
    hb[co*1024] = fmaxf(acc, 0.f);
  }
}

// conv2: 64->128, k4 s2 p1, ReLU.  grid (2 halves, 256n), block 256.
// thread: 4 spatial positions x 16 couts.
__global__ __launch_bounds__(256) void conv2_k(const float* __restrict__ h1,
                                               const float* __restrict__ wp,
                                               const float* __restrict__ b2,
                                               float* __restrict__ h2){
  __shared__ __align__(16) float hc[8*1024];
  __shared__ __align__(16) float wc[8*64*16];
  int n = blockIdx.y, half = blockIdx.x, t = threadIdx.x;
  int co0 = half*64;
  int pg = t&63, cg = t>>6;
  int ow = pg&15;
  float acc[4][16] = {};
  const float* h1b = h1 + (size_t)n*65536;
  for(int ci0=0; ci0<64; ci0+=8){
    __syncthreads();
    #pragma unroll
    for(int j=0;j<32;j++){ int f = j*256+t; hc[f] = h1b[((ci0 + (f>>10))<<10) + (f&1023)]; }
    #pragma unroll
    for(int j=0;j<32;j++){ int f = j*256+t; int c = f>>10, r = f&1023;
      wc[f] = wp[(((ci0+c)<<7) + co0)*16 + r]; }
    __syncthreads();
    for(int c=0;c<8;c++){
      float patch[4][16];
      #pragma unroll
      for(int j=0;j<4;j++){
        int oh = (pg>>4) + 4*j;
        #pragma unroll
        for(int kh=0;kh<4;kh++){
          int ih = 2*oh - 1 + kh;
          bool vr = (unsigned)ih < 32u;
          #pragma unroll
          for(int kw=0;kw<4;kw++){
            int iw = 2*ow - 1 + kw;
            patch[j][kh*4+kw] = (vr && (unsigned)iw<32u) ? hc[(c<<10) + (ih<<5) + iw] : 0.f;
          }
        }
      }
      #pragma unroll
      for(int co=0;co<16;co++){
        const float4* w4 = (const float4*)&wc[(c<<10) + ((cg*16+co)<<4)];
        float4 wa = w4[0], wb = w4[1], wcv = w4[2], wd = w4[3];
        #pragma unroll
        for(int j=0;j<4;j++){
          float s = patch[j][0]*wa.x + patch[j][1]*wa.y + patch[j][2]*wa.z + patch[j][3]*wa.w;
          s += patch[j][4]*wb.x + patch[j][5]*wb.y + patch[j][6]*wb.z + patch[j][7]*wb.w;
          s += patch[j][8]*wcv.x + patch[j][9]*wcv.y + patch[j][10]*wcv.z + patch[j][11]*wcv.w;
          s += patch[j][12]*wd.x + patch[j][13]*wd.y + patch[j][14]*wd.z + patch[j][15]*wd.w;
          acc[j][co] += s;
        }
      }
    }
  }
  #pragma unroll
  for(int co=0;co<16;co++){
    int coa = co0 + cg*16 + co;
    float bb = b2[coa];
    #pragma unroll
    for(int j=0;j<4;j++){
      h2[(size_t)(n*128 + coa)*256 + pg + 64*j] = fmaxf(acc[j][co] + bb, 0.f);
    }
  }
}

// conv3 (1x1): 128->256, no relu.  grid (4 co-blocks, 256n), block 256 = spatial.
__global__ __launch_bounds__(256) void conv3_k(const float* __restrict__ h2,
                                               const float* __restrict__ wT3,
                                               const float* __restrict__ b3,
                                               float* __restrict__ enc){
  __shared__ __align__(16) float hcs[32*256];
  __shared__ __align__(16) float wcs[32*64];
  int n = blockIdx.y, cb4 = blockIdx.x, t = threadIdx.x;
  int co0 = cb4*64;
  float acc[64] = {};
  for(int ci0=0; ci0<128; ci0+=32){
    __syncthreads();
    #pragma unroll
    for(int j=0;j<32;j++){ int f=j*256+t; hcs[f] = h2[(size_t)(n*128 + ci0 + (f>>8))*256 + (f&255)]; }
    #pragma unroll
    for(int j=0;j<8;j++){ int f=j*256+t; wcs[f] = wT3[(ci0 + (f>>6))*256 + co0 + (f&63)]; }
    __syncthreads();
    for(int c=0;c<32;c++){
      float e = hcs[(c<<8) + t];
      const float4* w4 = (const float4*)&wcs[c<<6];
      #pragma unroll
      for(int q=0;q<16;q++){
        float4 w = w4[q];
        acc[4*q+0] += e*w.x; acc[4*q+1] += e*w.y; acc[4*q+2] += e*w.z; acc[4*q+3] += e*w.w;
      }
    }
  }
  for(int co=0;co<64;co++)
    enc[(size_t)(n*256 + co0 + co)*256 + t] = acc[co] + b3[co0+co];
}

// VQ argmin over 256 codes; 16 rows per block; thread = code.
__global__ __launch_bounds__(256) void vq_argmin_k(const float* __restrict__ enc,
                                                   const float* __restrict__ cT,
                                                   const float* __restrict__ cn,
                                                   int* __restrict__ idx){
  __shared__ __align__(16) float el[16*32];
  __shared__ float dl[16*256];
  int r0 = blockIdx.x*16, t = threadIdx.x;
  float acc[16] = {};
  for(int d0=0; d0<256; d0+=32){
    __syncthreads();
    #pragma unroll
    for(int j=0;j<2;j++){ int f=j*256+t; el[f] = enc[(size_t)(r0 + (f>>5))*256 + d0 + (f&31)]; }
    __syncthreads();
    float ck[32];
    #pragma unroll
    for(int d=0; d<32; d++) ck[d] = cT[(d0+d)*256 + t];
    #pragma unroll
    for(int r=0;r<16;r++){
      const float4* e4 = (const float4*)&el[r*32];
      float s = 0.f;
      #pragma unroll
      for(int q=0;q<8;q++){
        float4 e = e4[q];
        s += e.x*ck[4*q] + e.y*ck[4*q+1] + e.z*ck[4*q+2] + e.w*ck[4*q+3];
      }
      acc[r] += s;
    }
  }
  float cnk = cn[t];
  __syncthreads();
  #pragma unroll
  for(int r=0;r<16;r++) dl[r*256 + t] = cnk - 2.f*acc[r];
  __syncthreads();
  int w = t>>6, l = t&63;
  for(int rr=0; rr<4; rr++){
    int r = w*4 + rr;
    float bv = dl[r*256 + l]; int bk = l;
    for(int q=1;q<4;q++){
      float v = dl[r*256 + q*64 + l]; int k = q*64 + l;
      if(v < bv || (v == bv && k < bk)){ bv = v; bk = k; }
    }
    for(int s=1;s<64;s<<=1){
      float ov = __shfl_xor(bv, s);
      int   ok = __shfl_xor(bk, s);
      if(ov < bv || (ov == bv && ok < bk)){ bv = ov; bk = ok; }
    }
    if(l==0) idx[r0 + r] = bk;
  }
}

// quantized = codebook[idx], and sum of (q-e)^2 for the loss.
__global__ __launch_bounds__(256) void quant_k(const float* __restrict__ enc,
                                               const float* __restrict__ cb,
                                               const int* __restrict__ idx,
                                               float* __restrict__ qnt,
                                               double* __restrict__ lacc){
  int g = blockIdx.x*256 + threadIdx.x;
  size_t base = (size_t)g*4;
  int r = (int)(base >> 8), d = (int)(base & 255);
  int k = idx[r];
  float4 e = *(const float4*)(enc + base);
  float4 q = *(const float4*)(cb + k*256 + d);
  *(float4*)(qnt + base) = q;
  float dx = q.x-e.x, dy = q.y-e.y, dz = q.z-e.z, dw = q.w-e.w;
  float s = dx*dx + dy*dy + dz*dz + dw*dw;
  for(int o=1;o<64;o<<=1) s += __shfl_xor(s, o);
  if((threadIdx.x & 63) == 0) atomicAdd(lacc, (double)s);
}

__global__ __launch_bounds__(256) void hist_k(const int* __restrict__ idx, int* __restrict__ hist){
  __shared__ int hl[256];
  int t = threadIdx.x;
  hl[t] = 0; __syncthreads();
  for(int j=0;j<8;j++) atomicAdd(&hl[idx[blockIdx.x*2048 + j*256 + t]], 1);
  __syncthreads();
  if(hl[t]) atomicAdd(&hist[t], hl[t]);
}

__global__ __launch_bounds__(256) void final_k(const int* __restrict__ hist,
                                               const double* __restrict__ lacc,
                                               float* __restrict__ out_lp){
  __shared__ float red[256];
  int t = threadIdx.x;
  float p = hist[t] * (1.f/65536.f);
  red[t] = p * logf(p + 1e-10f);
  __syncthreads();
  for(int s=128; s>0; s>>=1){ if(t<s) red[t] += red[t+s]; __syncthreads(); }
  if(t==0){
    out_lp[0] = 1.25f * (float)(*lacc / 16777216.0);
    out_lp[1] = expf(-red[0]);
  }
}

// dec1: convT 256->128 k4 s2 p1, ReLU. grid (8 co-blocks, 256n), block 256.
// thread: ow = t&31, ohb = t>>5; positions oh = ohb + 8j (j<4); 16 couts.
// Weight LDS [c][co][cl^(co&3)][tap] -> conflict-free reads (wave spans 4 cl).
__global__ __launch_bounds__(256) void dec1_k(const float* __restrict__ qnt,
                                              const float* __restrict__ wp,
                                              const float* __restrict__ db1,
                                              float* __restrict__ d1){
  __shared__ __align__(16) float qc[8*256];
  __shared__ __align__(16) float wl[8*16*16];   // [c][co][cl'][tap] = 2048 floats
  int n = blockIdx.y, cblk = blockIdx.x, t = threadIdx.x;
  int co0 = cblk*16;
  int ow = t&31, ohb = t>>5;
  int b = ow&1;
  int iwb = (ow + b) >> 1;
  bool mw0 = iwb < 16, mw1 = iwb >= 1;
  int iw0 = mw0 ? iwb : 0, iw1 = mw1 ? iwb-1 : 0;
  int a = ohb & 1;
  int cl = (a<<1) | b;
  int cx0 = ((cl^0)<<2), cx1 = ((cl^1)<<2), cx2 = ((cl^2)<<2), cx3 = ((cl^3)<<2);
  int ihb0 = (ohb + a) >> 1;
  float acc[4][16] = {};
  for(int ci0=0; ci0<256; ci0+=8){
    __syncthreads();
    #pragma unroll
    for(int j=0;j<8;j++){ int f=j*256+t; qc[f] = qnt[(size_t)(n*256 + ci0 + (f>>8))*256 + (f&255)]; }
    #pragma unroll
    for(int j=0;j<2;j++){
      int id = j*256+t;
      int cls = id>>7, cs = (id>>4)&7, cos = id&15;
      float4 w = *(const float4*)&wp[(size_t)((cls*256 + ci0 + cs)*128 + co0 + cos)*4];
      *(float4*)&wl[(cs<<8) + (cos<<4) + ((cls^(cos&3))<<2)] = w;
    }
    __syncthreads();
    for(int c=0;c<8;c++){
      float patch[4][4];
      #pragma unroll
      for(int j=0;j<4;j++){
        int ihb = ihb0 + 4*j;
        bool mh0 = ihb < 16, mh1 = ihb >= 1;
        int r0i = mh0 ? ihb : 0, r1i = mh1 ? ihb-1 : 0;
        patch[j][0] = (mh0 && mw0) ? qc[(c<<8) + (r0i<<4) + iw0] : 0.f;
        patch[j][1] = (mh0 && mw1) ? qc[(c<<8) + (r0i<<4) + iw1] : 0.f;
        patch[j][2] = (mh1 && mw0) ? qc[(c<<8) + (r1i<<4) + iw0] : 0.f;
        patch[j][3] = (mh1 && mw1) ? qc[(c<<8) + (r1i<<4) + iw1] : 0.f;
      }
      #pragma unroll
      for(int co=0;co<16;co++){
        int cx = ((co&3)==0) ? cx0 : ((co&3)==1) ? cx1 : ((co&3)==2) ? cx2 : cx3;
        const float4 w = *(const float4*)&wl[(c<<8) + (co<<4) + cx];
        #pragma unroll
        for(int j=0;j<4;j++)
          acc[j][co] += patch[j][0]*w.x + patch[j][1]*w.y + patch[j][2]*w.z + patch[j][3]*w.w;
      }
    }
  }
  #pragma unroll
  for(int co=0;co<16;co++){
    float bb = db1[co0+co];
    #pragma unroll
    for(int j=0;j<4;j++){
      int oh = ohb + 8*j;
      d1[(size_t)(n*128 + co0 + co)*1024 + oh*32 + ow] = fmaxf(acc[j][co] + bb, 0.f);
    }
  }
}

// dec2: convT 128->64 k4 s2 p1 + ReLU, fused with dec3 (1x1 64->3) + sigmoid.
// grid (16 = 8 oh-tiles x 2 ow-halves, 256n), block 256.
// thread: lw=t&31 (ow), s=t>>5: pg=s&1 (oh parity), cq=s>>1 (co quarter, 16 couts);
// 4 positions oh = oh0 + pg + 2q. acc[4][16] = 64 VGPR.
// Input staged with zero halo [c][6 rows][18 cols] (no masks in inner loop);
// weights [c][co][cl^(co&3)][tap] conflict-free, 16 FMA per ds_read_b128.
__global__ __launch_bounds__(256) void dec2_k(const float* __restrict__ d1,
                                              const float* __restrict__ wp,
                                              const float* __restrict__ db2,
                                              const float* __restrict__ dw3,
                                              const float* __restrict__ db3,
                                              float* __restrict__ dec){
  __shared__ __align__(16) float dc[8*108];     // [c][6][18], zero-filled halo
  __shared__ __align__(16) float wl[8*64*16];   // 32 KB; psum scratch in epilogue
  __shared__ float w3l[195];
  int n = blockIdx.y, tile = blockIdx.x, t = threadIdx.x;
  int oh0 = (tile>>1)*8, ow0 = (tile&1)*32;
  if(t < 192) w3l[t] = dw3[t];
  if(t < 3)   w3l[192+t] = db3[t];
  int lw = t&31, s = t>>5;
  int pg = s&1, cq = s>>1;
  int ow = ow0 + lw;
  int b = lw&1;
  int iwb = (ow + b) >> 1;
  int c0 = ow0/2 - 1;
  int liw = iwb - c0;          // in [1,17]
  int cl = (pg<<1) | b;
  int cx0 = ((cl^0)<<2), cx1 = ((cl^1)<<2), cx2 = ((cl^2)<<2), cx3 = ((cl^3)<<2);
  int ihr0 = oh0/2 - 1;
  float acc[4][16] = {};
  for(int ci0=0; ci0<128; ci0+=8){
    __syncthreads();
    #pragma unroll
    for(int j=0;j<4;j++){
      int f = j*256+t;
      if(f < 864){
        int c = f/108, rest = f%108;
        int rr = rest/18, col = rest%18;
        int ih = ihr0 + rr, iw = c0 + col;
        dc[f] = ((unsigned)ih < 32u && (unsigned)iw < 32u)
                ? d1[(size_t)(n*128 + ci0 + c)*1024 + ih*32 + iw] : 0.f;
      }
    }
    // stage weights: [cl][ci][co][tap] global -> [c][co][cl^(co&3)][tap] LDS
    #pragma unroll
    for(int j=0;j<8;j++){
      int f = j*256+t;
      int cls = f>>9, cs = (f>>6)&7, cos = f&63;
      float4 w = *(const float4*)&wp[(size_t)((cls*128 + ci0 + cs)<<8) + (cos<<2)];
      *(float4*)&wl[(cs<<10) + (cos<<4) + ((cls^(cos&3))<<2)] = w;
    }
    __syncthreads();
    for(int c=0;c<8;c++){
      float pr[5][2];
      #pragma unroll
      for(int r=0;r<5;r++){
        pr[r][0] = dc[c*108 + (pg+r)*18 + liw];
        pr[r][1] = dc[c*108 + (pg+r)*18 + liw - 1];
      }
      #pragma unroll
      for(int co=0;co<16;co++){
        int coa = (cq<<4) + co;
        int cx = ((co&3)==0) ? cx0 : ((co&3)==1) ? cx1 : ((co&3)==2) ? cx2 : cx3;
        const float4 w = *(const float4*)&wl[(c<<10) + (coa<<4) + cx];
        #pragma unroll
        for(int q=0;q<4;q++)
          acc[q][co] += pr[q+1][0]*w.x + pr[q+1][1]*w.y + pr[q][0]*w.z + pr[q][1]*w.w;
      }
    }
  }
  // bias + ReLU on this thread's 16 couts
  #pragma unroll
  for(int co=0;co<16;co++){
    float bb = db2[(cq<<4)+co];
    #pragma unroll
    for(int q=0;q<4;q++) acc[q][co] = fmaxf(acc[q][co] + bb, 0.f);
  }
  // partial 1x1 (dec3) over the 16 couts
  float z[4][3];
  #pragma unroll
  for(int q=0;q<4;q++)
    #pragma unroll
    for(int cp=0;cp<3;cp++){
      float sv = 0.f;
      #pragma unroll
      for(int co=0;co<16;co++) sv += acc[q][co]*w3l[((cq<<4)+co)*3+cp];
      z[q][cp] = sv;
    }
  __syncthreads();            // wl reads in main loop fully done
  if(cq != 0){
    #pragma unroll
    for(int q=0;q<4;q++)
      #pragma unroll
      for(int cp=0;cp<3;cp++) wl[t*12 + q*3 + cp] = z[q][cp];
  }
  __syncthreads();
  if(cq == 0){
    #pragma unroll
    for(int q=0;q<4;q++){
      int oh = oh0 + pg + 2*q;
      #pragma unroll
      for(int cp=0;cp<3;cp++){
        float zz = z[q][cp]
                 + wl[(((pg+2)<<5)+lw)*12 + q*3+cp]
                 + wl[(((pg+4)<<5)+lw)*12 + q*3+cp]
                 + wl[(((pg+6)<<5)+lw)*12 + q*3+cp]
                 + w3l[192+cp];
        dec[(size_t)(n*3 + cp)*4096 + oh*64 + ow] = 1.f/(1.f + expf(-zz));
      }
    }
  }
}

extern "C" void kernel_launch(void* const* d_in, const int* in_sizes, int n_in,
                              void* d_out, int out_size, void* d_ws, size_t ws_size,
                              hipStream_t stream) {
  const float* x   = (const float*)d_in[0];
  const float* ew1 = (const float*)d_in[1];
  const float* eb1 = (const float*)d_in[2];
  const float* ew2 = (const float*)d_in[3];
  const float* eb2 = (const float*)d_in[4];
  const float* ew3 = (const float*)d_in[5];
  const float* eb3 = (const float*)d_in[6];
  const float* cb  = (const float*)d_in[7];
  const float* dw1 = (const float*)d_in[8];
  const float* db1 = (const float*)d_in[9];
  const float* dw2 = (const float*)d_in[10];
  const float* db2 = (const float*)d_in[11];
  const float* dw3 = (const float*)d_in[12];
  const float* db3 = (const float*)d_in[13];

  float* out = (float*)d_out;
  float* dec = out;                           // 3,145,728
  float* enc = out + 3145728;                 // 16,777,216
  float* qnt = out + 19922944;                // 16,777,216
  float* lp  = out + 36700160;                // loss, perplexity

  float* ws = (float*)d_ws;
  float* d1buf = ws;                          // 33,554,432 floats (h1 aliases front)
  float* h1    = ws;                          // 16,777,216 (dead before dec1 writes)
  float* h2    = qnt;                         // reuse quantized slot (dead before quant_k)
  size_t o = 33554432;
  float* wc2p = ws + o; o += 131072;
  float* wd1p = ws + o; o += 524288;
  float* wd2p = ws + o; o += 131072;
  float* cT   = ws + o; o += 65536;
  float* cn   = ws + o; o += 256;
  float* wT3  = ws + o; o += 32768;
  int*   idx  = (int*)(ws + o); o += 65536;
  int*   hist = (int*)(ws + o); o += 256;
  double* lacc = (double*)(ws + o);

  zero_k<<<1, 256, 0, stream>>>(hist, lacc);
  prep_codebook_k<<<256, 256, 0, stream>>>(cb, cT, cn);
  prep_wT3_k<<<128, 256, 0, stream>>>(ew3, wT3);
  prep_weights_k<<<3072, 256, 0, stream>>>(ew2, dw1, dw2, wc2p, wd1p, wd2p);

  conv1_k<<<dim3(4,256), 256, 0, stream>>>(x, ew1, eb1, h1);
  conv2_k<<<dim3(2,256), 256, 0, stream>>>(h1, wc2p, eb2, h2);
  conv3_k<<<dim3(4,256), 256, 0, stream>>>(h2, wT3, eb3, enc);
  vq_argmin_k<<<4096, 256, 0, stream>>>(enc, cT, cn, idx);
  quant_k<<<16384, 256, 0, stream>>>(enc, cb, idx, qnt, lacc);
  hist_k<<<32, 256, 0, stream>>>(idx, hist);
  dec1_k<<<dim3(8,256), 256, 0, stream>>>(qnt, wd1p, db1, d1buf);
  dec2_k<<<dim3(16,256), 256, 0, stream>>>(d1buf, wd2p, db2, dw3, db3, dec);
  final_k<<<1, 256, 0, stream>>>(hist, lacc, lp);
}

// Round 6
// 2132.727 us; speedup vs baseline: 2.0904x; 1.8731x over previous
//
#include <hip/hip_runtime.h>
#include <math.h>

// ---------------------------------------------------------------------------
// VQ-VAE forward. Encoder + VQ in fp32 (outputs bit-identical), decoder in
// bf16 MFMA (16x16x32) as class-decomposed implicit GEMM.
// d_out: decoded | encoded | quantized | vq_loss | perplexity  (float32)
// R6: dec1/dec2 -> MFMA. qT gather (bf16 [n][sp][ci]); d1T class-major bf16;
//     dec2 fuses 1x1+sigmoid. Weights pre-packed bf16.
// ---------------------------------------------------------------------------

typedef __attribute__((ext_vector_type(8))) short bfrag;   // 8 bf16 = 4 VGPR
typedef __attribute__((ext_vector_type(4))) short bhalf4;  // 4 bf16 = 8 B
typedef __attribute__((ext_vector_type(4))) float ffrag;   // MFMA C/D

__device__ __forceinline__ short f2b(float x){              // f32->bf16 RNE
  unsigned u = __float_as_uint(x);
  unsigned r = (u + 0x7FFFu + ((u>>16)&1u)) >> 16;
  return (short)r;
}
__device__ __forceinline__ float b2f(short s){
  return __uint_as_float(((unsigned)(unsigned short)s) << 16);
}

__global__ __launch_bounds__(256) void zero_k(int* hist, double* lacc){
  int t = threadIdx.x;
  hist[t] = 0;
  if(t==0) *lacc = 0.0;
}

// codebook [256k][256d] -> cT[d][k], cn[k] = sum_d cb[k][d]^2
__global__ __launch_bounds__(256) void prep_codebook_k(const float* __restrict__ cb,
                                                       float* __restrict__ cT,
                                                       float* __restrict__ cn){
  int k = blockIdx.x, d = threadIdx.x;
  float v = cb[k*256 + d];
  cT[d*256 + k] = v;
  __shared__ float red[256];
  red[d] = v*v;
  __syncthreads();
  for(int s=128; s>0; s>>=1){ if(d<s) red[d] += red[d+s]; __syncthreads(); }
  if(d==0) cn[k] = red[0];
}

// w3 [256co][128ci] -> wT3[ci][co]
__global__ __launch_bounds__(256) void prep_wT3_k(const float* __restrict__ w3,
                                                  float* __restrict__ wT3){
  int ci = blockIdx.x, co = threadIdx.x;
  wT3[ci*256 + co] = w3[co*128 + ci];
}

// Weight re-layouts:
//  conv2:  wc2[ci64][co128][k16] f32      = w2[co][ci][k]
//  dec1:   wd1b[cl][tap][co128][ci256] bf16 = dw1[ci][co][kh(a,i)][kw(b,j)]
//  dec2:   wd2b[cl][tap][co64][ci128]  bf16 = dw2[ci][co][kh(a,i)][kw(b,j)]
//  cl = a*2+b (a=oh&1,b=ow&1); tap=i*2+j reads input row p+da-i, col r+db-j;
//  a==0 -> kh=1+2i ; a==1 -> kh=2i  (same for kw/b).
__global__ __launch_bounds__(256) void prep_weights_k(const float* __restrict__ w2,
                                                      const float* __restrict__ dw1,
                                                      const float* __restrict__ dw2,
                                                      float* __restrict__ wc2,
                                                      short* __restrict__ wd1b,
                                                      short* __restrict__ wd2b){
  int gid = blockIdx.x*256 + threadIdx.x;
  if(gid < 131072){
    int id = gid; int ci = id>>11, co = (id>>4)&127, k = id&15;
    wc2[id] = w2[((co<<6) + ci)*16 + k];
  } else if(gid < 655360){
    int id = gid - 131072;
    int ci = id&255, co = (id>>8)&127, tp = (id>>15)&3, cl = id>>17;
    int a = cl>>1, b = cl&1, i = tp>>1, j = tp&1;
    int kh = a ? 2*i : 1+2*i;
    int kw = b ? 2*j : 1+2*j;
    wd1b[id] = f2b(dw1[((ci<<7) + co)*16 + kh*4 + kw]);
  } else {
    int id = gid - 655360;
    int ci = id&127, co = (id>>7)&63, tp = (id>>13)&3, cl = id>>15;
    int a = cl>>1, b = cl&1, i = tp>>1, j = tp&1;
    int kh = a ? 2*i : 1+2*i;
    int kw = b ? 2*j : 1+2*j;
    wd2b[id] = f2b(dw2[((ci<<6) + co)*16 + kh*4 + kw]);
  }
}

// conv1: 3->64, k4 s2 p1, ReLU.  grid (4, 256n), block 256.
__global__ __launch_bounds__(256) void conv1_k(const float* __restrict__ x,
                                               const float* __restrict__ w1,
                                               const float* __restrict__ b1,
                                               float* __restrict__ h1){
  __shared__ __align__(16) float wl[64*48];
  __shared__ float bl[64];
  int n = blockIdx.y, qd = blockIdx.x, t = threadIdx.x;
  for(int j=t; j<3072; j+=256) wl[j] = w1[j];
  if(t < 64) bl[t] = b1[t];
  __syncthreads();
  int oh = qd*8 + (t>>5), ow = t&31;
  const float* xb = x + n*3*4096;
  float patch[48];
  #pragma unroll
  for(int c=0;c<3;c++)
    #pragma unroll
    for(int kh=0;kh<4;kh++){
      int ih = 2*oh - 1 + kh;
      bool vr = (unsigned)ih < 64u;
      #pragma unroll
      for(int kw=0;kw<4;kw++){
        int iw = 2*ow - 1 + kw;
        patch[c*16 + kh*4 + kw] = (vr && (unsigned)iw<64u) ? xb[c*4096 + ih*64 + iw] : 0.f;
      }
    }
  float* hb = h1 + (size_t)n*64*1024 + oh*32 + ow;
  for(int co=0; co<64; co++){
    float acc = bl[co];
    #pragma unroll
    for(int k2=0;k2<48;k2++) acc += patch[k2]*wl[co*48 + k2];
    hb[co*1024] = fmaxf(acc, 0.f);
  }
}

// conv2: 64->128, k4 s2 p1, ReLU.  grid (2 halves, 256n), block 256.
__global__ __launch_bounds__(256) void conv2_k(const float* __restrict__ h1,
                                               const float* __restrict__ wp,
                                               const float* __restrict__ b2,
                                               float* __restrict__ h2){
  __shared__ __align__(16) float hc[8*1024];
  __shared__ __align__(16) float wc[8*64*16];
  int n = blockIdx.y, half = blockIdx.x, t = threadIdx.x;
  int co0 = half*64;
  int pg = t&63, cg = t>>6;
  int ow = pg&15;
  float acc[4][16] = {};
  const float* h1b = h1 + (size_t)n*65536;
  for(int ci0=0; ci0<64; ci0+=8){
    __syncthreads();
    #pragma unroll
    for(int j=0;j<32;j++){ int f = j*256+t; hc[f] = h1b[((ci0 + (f>>10))<<10) + (f&1023)]; }
    #pragma unroll
    for(int j=0;j<32;j++){ int f = j*256+t; int c = f>>10, r = f&1023;
      wc[f] = wp[(((ci0+c)<<7) + co0)*16 + r]; }
    __syncthreads();
    for(int c=0;c<8;c++){
      float patch[4][16];
      #pragma unroll
      for(int j=0;j<4;j++){
        int oh = (pg>>4) + 4*j;
        #pragma unroll
        for(int kh=0;kh<4;kh++){
          int ih = 2*oh - 1 + kh;
          bool vr = (unsigned)ih < 32u;
          #pragma unroll
          for(int kw=0;kw<4;kw++){
            int iw = 2*ow - 1 + kw;
            patch[j][kh*4+kw] = (vr && (unsigned)iw<32u) ? hc[(c<<10) + (ih<<5) + iw] : 0.f;
          }
        }
      }
      #pragma unroll
      for(int co=0;co<16;co++){
        const float4* w4 = (const float4*)&wc[(c<<10) + ((cg*16+co)<<4)];
        float4 wa = w4[0], wb = w4[1], wcv = w4[2], wd = w4[3];
        #pragma unroll
        for(int j=0;j<4;j++){
          float s = patch[j][0]*wa.x + patch[j][1]*wa.y + patch[j][2]*wa.z + patch[j][3]*wa.w;
          s += patch[j][4]*wb.x + patch[j][5]*wb.y + patch[j][6]*wb.z + patch[j][7]*wb.w;
          s += patch[j][8]*wcv.x + patch[j][9]*wcv.y + patch[j][10]*wcv.z + patch[j][11]*wcv.w;
          s += patch[j][12]*wd.x + patch[j][13]*wd.y + patch[j][14]*wd.z + patch[j][15]*wd.w;
          acc[j][co] += s;
        }
      }
    }
  }
  #pragma unroll
  for(int co=0;co<16;co++){
    int coa = co0 + cg*16 + co;
    float bb = b2[coa];
    #pragma unroll
    for(int j=0;j<4;j++){
      h2[(size_t)(n*128 + coa)*256 + pg + 64*j] = fmaxf(acc[j][co] + bb, 0.f);
    }
  }
}

// conv3 (1x1): 128->256.  grid (4 co-blocks, 256n), block 256 = spatial.
__global__ __launch_bounds__(256) void conv3_k(const float* __restrict__ h2,
                                               const float* __restrict__ wT3,
                                               const float* __restrict__ b3,
                                               float* __restrict__ enc){
  __shared__ __align__(16) float hcs[32*256];
  __shared__ __align__(16) float wcs[32*64];
  int n = blockIdx.y, cb4 = blockIdx.x, t = threadIdx.x;
  int co0 = cb4*64;
  float acc[64] = {};
  for(int ci0=0; ci0<128; ci0+=32){
    __syncthreads();
    #pragma unroll
    for(int j=0;j<32;j++){ int f=j*256+t; hcs[f] = h2[(size_t)(n*128 + ci0 + (f>>8))*256 + (f&255)]; }
    #pragma unroll
    for(int j=0;j<8;j++){ int f=j*256+t; wcs[f] = wT3[(ci0 + (f>>6))*256 + co0 + (f&63)]; }
    __syncthreads();
    for(int c=0;c<32;c++){
      float e = hcs[(c<<8) + t];
      const float4* w4 = (const float4*)&wcs[c<<6];
      #pragma unroll
      for(int q=0;q<16;q++){
        float4 w = w4[q];
        acc[4*q+0] += e*w.x; acc[4*q+1] += e*w.y; acc[4*q+2] += e*w.z; acc[4*q+3] += e*w.w;
      }
    }
  }
  for(int co=0;co<64;co++)
    enc[(size_t)(n*256 + co0 + co)*256 + t] = acc[co] + b3[co0+co];
}

// VQ argmin over 256 codes; 16 rows per block; thread = code.
__global__ __launch_bounds__(256) void vq_argmin_k(const float* __restrict__ enc,
                                                   const float* __restrict__ cT,
                                                   const float* __restrict__ cn,
                                                   int* __restrict__ idx){
  __shared__ __align__(16) float el[16*32];
  __shared__ float dl[16*256];
  int r0 = blockIdx.x*16, t = threadIdx.x;
  float acc[16] = {};
  for(int d0=0; d0<256; d0+=32){
    __syncthreads();
    #pragma unroll
    for(int j=0;j<2;j++){ int f=j*256+t; el[f] = enc[(size_t)(r0 + (f>>5))*256 + d0 + (f&31)]; }
    __syncthreads();
    float ck[32];
    #pragma unroll
    for(int d=0; d<32; d++) ck[d] = cT[(d0+d)*256 + t];
    #pragma unroll
    for(int r=0;r<16;r++){
      const float4* e4 = (const float4*)&el[r*32];
      float s = 0.f;
      #pragma unroll
      for(int q=0;q<8;q++){
        float4 e = e4[q];
        s += e.x*ck[4*q] + e.y*ck[4*q+1] + e.z*ck[4*q+2] + e.w*ck[4*q+3];
      }
      acc[r] += s;
    }
  }
  float cnk = cn[t];
  __syncthreads();
  #pragma unroll
  for(int r=0;r<16;r++) dl[r*256 + t] = cnk - 2.f*acc[r];
  __syncthreads();
  int w = t>>6, l = t&63;
  for(int rr=0; rr<4; rr++){
    int r = w*4 + rr;
    float bv = dl[r*256 + l]; int bk = l;
    for(int q=1;q<4;q++){
      float v = dl[r*256 + q*64 + l]; int k = q*64 + l;
      if(v < bv || (v == bv && k < bk)){ bv = v; bk = k; }
    }
    for(int s=1;s<64;s<<=1){
      float ov = __shfl_xor(bv, s);
      int   ok = __shfl_xor(bk, s);
      if(ov < bv || (ov == bv && ok < bk)){ bv = ov; bk = ok; }
    }
    if(l==0) idx[r0 + r] = bk;
  }
}

// quantized = codebook[idx] (fp32 output) + loss accumulation.
__global__ __launch_bounds__(256) void quant_k(const float* __restrict__ enc,
                                               const float* __restrict__ cb,
                                               const int* __restrict__ idx,
                                               float* __restrict__ qnt,
                                               double* __restrict__ lacc){
  int g = blockIdx.x*256 + threadIdx.x;
  size_t base = (size_t)g*4;
  int r = (int)(base >> 8), d = (int)(base & 255);
  int k = idx[r];
  float4 e = *(const float4*)(enc + base);
  float4 q = *(const float4*)(cb + k*256 + d);
  *(float4*)(qnt + base) = q;
  float dx = q.x-e.x, dy = q.y-e.y, dz = q.z-e.z, dw = q.w-e.w;
  float s = dx*dx + dy*dy + dz*dz + dw*dw;
  for(int o=1;o<64;o<<=1) s += __shfl_xor(s, o);
  if((threadIdx.x & 63) == 0) atomicAdd(lacc, (double)s);
}

// qT[n][sp 256][c 256] bf16 = cb[idx[n*256+c]][sp].  grid 256 (n), block 256.
__global__ __launch_bounds__(256) void gatherT_k(const float* __restrict__ cb,
                                                 const int* __restrict__ idx,
                                                 short* __restrict__ qT){
  int n = blockIdx.x, t = threadIdx.x;
  int cpair = (t&127)<<1;
  int dbase = (t>>7)<<7;
  int k0 = idx[(n<<8)+cpair];
  int k1 = idx[(n<<8)+cpair+1];
  const float* r0 = cb + (k0<<8);
  const float* r1 = cb + (k1<<8);
  short* outb = qT + (n<<16) + cpair;
  for(int d=dbase; d<dbase+128; d+=4){
    float4 a = *(const float4*)(r0+d);
    float4 b = *(const float4*)(r1+d);
    unsigned p0 = ((unsigned)(unsigned short)f2b(a.x)) | (((unsigned)(unsigned short)f2b(b.x))<<16);
    unsigned p1 = ((unsigned)(unsigned short)f2b(a.y)) | (((unsigned)(unsigned short)f2b(b.y))<<16);
    unsigned p2 = ((unsigned)(unsigned short)f2b(a.z)) | (((unsigned)(unsigned short)f2b(b.z))<<16);
    unsigned p3 = ((unsigned)(unsigned short)f2b(a.w)) | (((unsigned)(unsigned short)f2b(b.w))<<16);
    *(unsigned*)(outb + ((d+0)<<8)) = p0;
    *(unsigned*)(outb + ((d+1)<<8)) = p1;
    *(unsigned*)(outb + ((d+2)<<8)) = p2;
    *(unsigned*)(outb + ((d+3)<<8)) = p3;
  }
}

__global__ __launch_bounds__(256) void hist_k(const int* __restrict__ idx, int* __restrict__ hist){
  __shared__ int hl[256];
  int t = threadIdx.x;
  hl[t] = 0; __syncthreads();
  for(int j=0;j<8;j++) atomicAdd(&hl[idx[blockIdx.x*2048 + j*256 + t]], 1);
  __syncthreads();
  if(hl[t]) atomicAdd(&hist[t], hl[t]);
}

__global__ __launch_bounds__(256) void final_k(const int* __restrict__ hist,
                                               const double* __restrict__ lacc,
                                               float* __restrict__ out_lp){
  __shared__ float red[256];
  int t = threadIdx.x;
  float p = hist[t] * (1.f/65536.f);
  red[t] = p * logf(p + 1e-10f);
  __syncthreads();
  for(int s=128; s>0; s>>=1){ if(t<s) red[t] += red[t+s]; __syncthreads(); }
  if(t==0){
    out_lp[0] = 1.25f * (float)(*lacc / 16777216.0);
    out_lp[1] = expf(-red[0]);
  }
}

// dec1 MFMA: convT 256->128 k4 s2 p1 + ReLU, per (n, class) implicit GEMM.
// C[co128][pos256] = sum_tap W[co][ci] x Qshift[ci][pos]; K=ci=256, 8 steps.
// grid (4 cl, 256 n), 512 thr (8 waves: wr=wv&1 co-half, nq=wv>>1 pos quarter).
// B tile: q halo 17x17 x 32ci bf16, pitch 40 (conflict-free). A from global (L2).
// Output d1T[n][cl][p16][r16][ci128] bf16, coalesced via C-LDS two-pass.
__global__ __launch_bounds__(512,4) void dec1_mfma(const short* __restrict__ qT,
                                                   const short* __restrict__ wb,
                                                   const float* __restrict__ db1,
                                                   short* __restrict__ d1T){
  __shared__ short smem[17408];     // max(B 289*40=11560, C 256*68=17408)
  int n = blockIdx.y, cl = blockIdx.x, t = threadIdx.x;
  int da = cl>>1, db = cl&1;
  int l = t&63, wv = t>>6;
  int m0 = (wv&1)<<6;
  int nq = wv>>1;
  int lc = l&15, lk = l>>4;
  ffrag acc[4][4] = {};
  const short* wbase = wb + cl*131072;
  for(int ci0=0; ci0<256; ci0+=32){
    __syncthreads();
    #pragma unroll
    for(int jj=0;jj<2;jj++){
      int id = jj*512 + t;
      if(id < 578){
        int cell = id>>1, half = id&1;
        int hr = cell/17, hc = cell - hr*17;
        int h = hr + da - 1, w = hc + db - 1;
        bfrag v0 = {}, v1 = {};
        if((unsigned)h < 16u && (unsigned)w < 16u){
          const short* src = qT + (((n<<8) + (h<<4) + w)<<8) + ci0 + (half<<4);
          v0 = *(const bfrag*)src;
          v1 = *(const bfrag*)(src+8);
        }
        short* dst = smem + cell*40 + (half<<4);
        *(bfrag*)dst = v0;
        *(bfrag*)(dst+8) = v1;
      }
    }
    __syncthreads();
    #pragma unroll
    for(int tap=0; tap<4; tap++){
      const int i = tap>>1, j = tap&1;
      bfrag aF[4], bF[4];
      #pragma unroll
      for(int mi=0;mi<4;mi++){
        int co = m0 + mi*16 + lc;
        aF[mi] = *(const bfrag*)(wbase + (tap*128 + co)*256 + ci0 + (lk<<3));
      }
      #pragma unroll
      for(int ni=0;ni<4;ni++){
        int p = (nq<<2) + ni;
        int sp = (p+1-i)*17 + lc + 1 - j;
        bF[ni] = *(const bfrag*)(smem + sp*40 + (lk<<3));
      }
      #pragma unroll
      for(int mi=0;mi<4;mi++)
        #pragma unroll
        for(int ni=0;ni<4;ni++)
          acc[mi][ni] = __builtin_amdgcn_mfma_f32_16x16x32_bf16(aF[mi], bF[ni], acc[mi][ni], 0, 0, 0);
    }
  }
  short* gout = d1T + (size_t)((n<<2)+cl)*32768;
  #pragma unroll
  for(int h=0; h<2; h++){
    __syncthreads();
    if((wv&1)==h){
      #pragma unroll
      for(int mi=0;mi<4;mi++){
        int col = mi*16 + (lk<<2);
        int cog = (h<<6) + col;
        float b0 = db1[cog], b1 = db1[cog+1], b2 = db1[cog+2], b3 = db1[cog+3];
        #pragma unroll
        for(int ni=0;ni<4;ni++){
          int pos = (nq<<6) + ni*16 + lc;
          bhalf4 pk;
          pk[0] = f2b(fmaxf(acc[mi][ni][0]+b0, 0.f));
          pk[1] = f2b(fmaxf(acc[mi][ni][1]+b1, 0.f));
          pk[2] = f2b(fmaxf(acc[mi][ni][2]+b2, 0.f));
          pk[3] = f2b(fmaxf(acc[mi][ni][3]+b3, 0.f));
          *(bhalf4*)(smem + pos*68 + col) = pk;
        }
      }
    }
    __syncthreads();
    #pragma unroll
    for(int q=0;q<8;q++){
      int s = (q<<11) + (t<<2);
      int pos = s>>6, wi = s&63;
      bhalf4 v = *(const bhalf4*)(smem + pos*68 + wi);
      *(bhalf4*)(gout + (pos<<7) + (h<<6) + wi) = v;
    }
  }
}

// dec2 MFMA: convT 128->64 k4 s2 p1 + ReLU + fused 1x1(64->3) + sigmoid.
// grid (8 = 4 cl x 2 p-halves, 256 n), 512 thr (8 waves: wave = 64co x 64pos).
// B tile: d1 halo 17x33 x 32ci bf16 pitch 40; A from global; K=128, 4 steps.
__global__ __launch_bounds__(512,4) void dec2_mfma(const short* __restrict__ d1T,
                                                   const short* __restrict__ wb,
                                                   const float* __restrict__ db2,
                                                   const float* __restrict__ dw3,
                                                   const float* __restrict__ db3,
                                                   float* __restrict__ dec){
  __shared__ short smem[22440];     // max(B 561*40=22440, C 256*68=17408)
  __shared__ float w3s[196];
  int n = blockIdx.y, bx = blockIdx.x;
  int cl = bx&3, ph = bx>>2;
  int da = cl>>1, db = cl&1;
  int t = threadIdx.x, l = t&63, wv = t>>6;
  int lc = l&15, lk = l>>4;
  if(t<195) w3s[t] = (t<192) ? dw3[t] : db3[t-192];
  ffrag acc[4][4] = {};
  const short* wbase = wb + cl*32768;
  int P0 = ph<<4;
  for(int ci0=0; ci0<128; ci0+=32){
    __syncthreads();
    #pragma unroll
    for(int jj=0;jj<3;jj++){
      int id = jj*512 + t;
      if(id < 1122){
        int cell = id>>1, half = id&1;
        int hr = cell/33, hc = cell - hr*33;
        int h = P0 + da - 1 + hr;
        int w = hc + db - 1;
        bfrag v0 = {}, v1 = {};
        if((unsigned)h < 32u && (unsigned)w < 32u){
          int cl2 = ((h&1)<<1) | (w&1);
          const short* src = d1T + (size_t)((((n<<2)+cl2)<<8) + ((h>>1)<<4) + (w>>1))*128 + ci0 + (half<<4);
          v0 = *(const bfrag*)src;
          v1 = *(const bfrag*)(src+8);
        }
        short* dst = smem + cell*40 + (half<<4);
        *(bfrag*)dst = v0;
        *(bfrag*)(dst+8) = v1;
      }
    }
    __syncthreads();
    #pragma unroll
    for(int tap=0; tap<4; tap++){
      const int i = tap>>1, j = tap&1;
      bfrag aF[4], bF[4];
      #pragma unroll
      for(int mi=0;mi<4;mi++){
        int co = mi*16 + lc;
        aF[mi] = *(const bfrag*)(wbase + (tap*64 + co)*128 + ci0 + (lk<<3));
      }
      #pragma unroll
      for(int ni=0;ni<4;ni++){
        int pos = (wv<<6) + (ni<<4);
        int prel = pos>>5;
        int rb = pos&31;
        int sp = (prel+1-i)*33 + rb + lc + 1 - j;
        bF[ni] = *(const bfrag*)(smem + sp*40 + (lk<<3));
      }
      #pragma unroll
      for(int mi=0;mi<4;mi++)
        #pragma unroll
        for(int ni=0;ni<4;ni++)
          acc[mi][ni] = __builtin_amdgcn_mfma_f32_16x16x32_bf16(aF[mi], bF[ni], acc[mi][ni], 0, 0, 0);
    }
  }
  #pragma unroll
  for(int hh=0; hh<2; hh++){
    __syncthreads();
    if((wv>>2)==hh){
      #pragma unroll
      for(int mi=0;mi<4;mi++){
        int cob = mi*16 + (lk<<2);
        float b0=db2[cob], b1=db2[cob+1], b2=db2[cob+2], b3=db2[cob+3];
        #pragma unroll
        for(int ni=0;ni<4;ni++){
          int posl = ((wv&3)<<6) + (ni<<4) + lc;
          bhalf4 pk;
          pk[0] = f2b(fmaxf(acc[mi][ni][0]+b0, 0.f));
          pk[1] = f2b(fmaxf(acc[mi][ni][1]+b1, 0.f));
          pk[2] = f2b(fmaxf(acc[mi][ni][2]+b2, 0.f));
          pk[3] = f2b(fmaxf(acc[mi][ni][3]+b3, 0.f));
          *(bhalf4*)(smem + posl*68 + cob) = pk;
        }
      }
    }
    __syncthreads();
    {
      int posl = t>>1, ch = t&1;
      float z0=0.f, z1=0.f, z2=0.f;
      #pragma unroll
      for(int q=0;q<8;q++){
        bhalf4 v = *(const bhalf4*)(smem + posl*68 + (ch<<5) + (q<<2));
        #pragma unroll
        for(int e=0;e<4;e++){
          float f = b2f(v[e]);
          int co = (ch<<5) + (q<<2) + e;
          z0 += f*w3s[co*3+0];
          z1 += f*w3s[co*3+1];
          z2 += f*w3s[co*3+2];
        }
      }
      z0 += __shfl_xor(z0,1); z1 += __shfl_xor(z1,1); z2 += __shfl_xor(z2,1);
      if(ch==0){
        int pos = (hh<<8) + posl;
        int p = P0 + (pos>>5), r = pos&31;
        int oh = (p<<1)+da, ow = (r<<1)+db;
        size_t o = ((size_t)n*3)*4096 + (oh<<6) + ow;
        z0 += w3s[192]; z1 += w3s[193]; z2 += w3s[194];
        dec[o]      = 1.f/(1.f+expf(-z0));
        dec[o+4096] = 1.f/(1.f+expf(-z1));
        dec[o+8192] = 1.f/(1.f+expf(-z2));
      }
    }
  }
}

extern "C" void kernel_launch(void* const* d_in, const int* in_sizes, int n_in,
                              void* d_out, int out_size, void* d_ws, size_t ws_size,
                              hipStream_t stream) {
  const float* x   = (const float*)d_in[0];
  const float* ew1 = (const float*)d_in[1];
  const float* eb1 = (const float*)d_in[2];
  const float* ew2 = (const float*)d_in[3];
  const float* eb2 = (const float*)d_in[4];
  const float* ew3 = (const float*)d_in[5];
  const float* eb3 = (const float*)d_in[6];
  const float* cb  = (const float*)d_in[7];
  const float* dw1 = (const float*)d_in[8];
  const float* db1 = (const float*)d_in[9];
  const float* dw2 = (const float*)d_in[10];
  const float* db2 = (const float*)d_in[11];
  const float* dw3 = (const float*)d_in[12];
  const float* db3 = (const float*)d_in[13];

  float* out = (float*)d_out;
  float* dec = out;                           // 3,145,728
  float* enc = out + 3145728;                 // 16,777,216
  float* qnt = out + 19922944;                // 16,777,216
  float* lp  = out + 36700160;                // loss, perplexity

  float* ws = (float*)d_ws;
  float* h1  = ws;                            // 16,777,216 f (dead before dec1)
  short* d1T = (short*)ws;                    // 33,554,432 sh (aliases h1 region)
  float* h2  = qnt;                           // reuse quantized slot
  size_t o = 16777216;
  float* wc2p = ws + o; o += 131072;
  short* qTb  = (short*)(ws + o); o += 8388608;   // 16,777,216 shorts
  short* wd1b = (short*)(ws + o); o += 262144;    // 524,288 shorts
  short* wd2b = (short*)(ws + o); o += 65536;     // 131,072 shorts
  float* cT   = ws + o; o += 65536;
  float* cn   = ws + o; o += 256;
  float* wT3  = ws + o; o += 32768;
  int*   idx  = (int*)(ws + o); o += 65536;
  int*   hist = (int*)(ws + o); o += 256;
  double* lacc = (double*)(ws + o);

  zero_k<<<1, 256, 0, stream>>>(hist, lacc);
  prep_codebook_k<<<256, 256, 0, stream>>>(cb, cT, cn);
  prep_wT3_k<<<128, 256, 0, stream>>>(ew3, wT3);
  prep_weights_k<<<3072, 256, 0, stream>>>(ew2, dw1, dw2, wc2p, wd1b, wd2b);

  conv1_k<<<dim3(4,256), 256, 0, stream>>>(x, ew1, eb1, h1);
  conv2_k<<<dim3(2,256), 256, 0, stream>>>(h1, wc2p, eb2, h2);
  conv3_k<<<dim3(4,256), 256, 0, stream>>>(h2, wT3, eb3, enc);
  vq_argmin_k<<<4096, 256, 0, stream>>>(enc, cT, cn, idx);
  gatherT_k<<<256, 256, 0, stream>>>(cb, idx, qTb);
  quant_k<<<16384, 256, 0, stream>>>(enc, cb, idx, qnt, lacc);
  hist_k<<<32, 256, 0, stream>>>(idx, hist);
  dec1_mfma<<<dim3(4,256), 512, 0, stream>>>(qTb, wd1b, db1, d1T);
  dec2_mfma<<<dim3(8,256), 512, 0, stream>>>(d1T, wd2b, db2, dw3, db3, dec);
  final_k<<<1, 256, 0, stream>>>(hist, lacc, lp);
}